// Round 1
// baseline (113.951 us; speedup 1.0000x reference)
//
#include <hip/hip_runtime.h>
#include <cmath>
#include <complex>

#ifndef M_PI
#define M_PI 3.14159265358979323846
#endif

namespace {

constexpr int NT     = 128;            // threads per block
constexpr int CHUNK  = 64;             // samples per thread
constexpr int WARM   = 64;             // warm-up samples; |p_max|^64 = 0.7577^64 ~ 2e-8
constexpr int REGION = NT * CHUNK;     // 8192 samples per block
constexpr int T_LEN  = 65536;          // time length per batch row

struct Coefs { float b0, b1, b2, b3, b4, a1, a2, a3, a4; };

// Owner-major rows of 64 floats. XOR-swizzle the 16 float4-groups per row so
// every phase's ds_*_b128 spreads uniformly over the 32 banks (8 words/bank,
// the b128 floor). Unswizzled stride-64 would put all 64 lanes on 4 banks.
__device__ __forceinline__ int lds_addr4(int o, int tg) {
    return (o << 6) + ((tg ^ (o & 15)) << 2);
}

__global__ __launch_bounds__(NT, 2) void butter_kernel(
        const float* __restrict__ x, float* __restrict__ y, Coefs c) {
    __shared__ float lds[(NT + 1) * 64];   // 33 KB: warm row (o=0) + NT chunk rows

    const int tid = threadIdx.x;
    const int bpr = T_LEN / REGION;        // 8 blocks per row
    const int row = blockIdx.x / bpr;
    const int bir = blockIdx.x % bpr;
    const size_t base = (size_t)row * T_LEN + (size_t)bir * REGION;
    const float4* __restrict__ xin = (const float4*)(x + base);

    // ---- Phase 1: stage warm-up row + region into LDS (coalesced float4) ----
    if (tid < WARM / 4) {
        float4 v = make_float4(0.f, 0.f, 0.f, 0.f);   // row start: zero state is exact
        if (bir != 0) v = ((const float4*)(x + base - WARM))[tid];
        *(float4*)&lds[lds_addr4(0, tid)] = v;
    }
#pragma unroll
    for (int k = 0; k < REGION / 4 / NT; ++k) {       // 16 iters
        int i4 = k * NT + tid;                        // global float4 idx in region
        float4 v = xin[i4];
        int o  = (i4 >> 4) + 1;                       // 16 float4 groups per chunk
        int tg = i4 & 15;
        *(float4*)&lds[lds_addr4(o, tg)] = v;
    }
    __syncthreads();

    float z0 = 0.f, z1 = 0.f, z2 = 0.f, z3 = 0.f;

    // DF2T step, matching the reference exactly (fp32 coefficients):
    //   y  = b0*x + z0
    //   z0 = z1 + b1*x - a1*y ; z1 = z2 + b2*x - a2*y
    //   z2 = z3 + b3*x - a3*y ; z3 =      b4*x - a4*y
#define STEP_Y(xv, yv)                                   \
    do {                                                 \
        yv = fmaf(c.b0, (xv), z0);                       \
        z0 = fmaf(-c.a1, (yv), fmaf(c.b1, (xv), z1));    \
        z1 = fmaf(-c.a2, (yv), fmaf(c.b2, (xv), z2));    \
        z2 = fmaf(-c.a3, (yv), fmaf(c.b3, (xv), z3));    \
        z3 = fmaf(-c.a4, (yv), c.b4 * (xv));             \
    } while (0)

    // ---- Phase 2: warm-up over previous chunk (owner = tid); discard y ----
#pragma unroll
    for (int tg = 0; tg < WARM / 4; ++tg) {
        float4 xv = *(const float4*)&lds[lds_addr4(tid, tg)];
        float yd;
        STEP_Y(xv.x, yd); STEP_Y(xv.y, yd); STEP_Y(xv.z, yd); STEP_Y(xv.w, yd);
        (void)yd;
    }
    __syncthreads();   // main phase overwrites chunks other threads warm up from

    // ---- Phase 3: main chunk (owner = tid+1); y overwrites x in LDS ----
#pragma unroll
    for (int tg = 0; tg < CHUNK / 4; ++tg) {
        int a = lds_addr4(tid + 1, tg);
        float4 xv = *(const float4*)&lds[a];
        float4 yv;
        STEP_Y(xv.x, yv.x); STEP_Y(xv.y, yv.y); STEP_Y(xv.z, yv.z); STEP_Y(xv.w, yv.w);
        *(float4*)&lds[a] = yv;
    }
    __syncthreads();

    // ---- Phase 4: coalesced float4 store ----
    float4* __restrict__ yout = (float4*)(y + base);
#pragma unroll
    for (int k = 0; k < REGION / 4 / NT; ++k) {
        int i4 = k * NT + tid;
        int o  = (i4 >> 4) + 1;
        int tg = i4 & 15;
        yout[i4] = *(const float4*)&lds[lds_addr4(o, tg)];
    }
#undef STEP_Y
}

// Host-side coefficient design: identical math to the reference (double
// precision bilinear-transformed 4th-order Butterworth, cast to fp32).
Coefs make_coefs() {
    const int ORDER = 4;
    const double wn  = 4000.0 / (0.5 * 16000.0);   // 0.5
    const double fs2 = 4.0;
    const double warped = fs2 * std::tan(M_PI * wn / 4.0);
    std::complex<double> pd[4];
    std::complex<double> prod(1.0, 0.0);
    for (int k = 1; k <= ORDER; ++k) {
        double ang = M_PI * (2.0 * k + ORDER - 1.0) / (2.0 * ORDER);
        std::complex<double> p = warped * std::exp(std::complex<double>(0.0, ang));
        prod *= (fs2 - p);
        pd[k - 1] = (fs2 + p) / (fs2 - p);
    }
    double kd = std::pow(warped, ORDER) / prod.real();
    double b[5] = { kd, 4.0 * kd, 6.0 * kd, 4.0 * kd, kd };  // kd * poly(-ones(4))
    std::complex<double> a[5] = { {1,0}, {0,0}, {0,0}, {0,0}, {0,0} };
    for (int k = 0; k < ORDER; ++k)
        for (int j = k + 1; j >= 1; --j) a[j] -= pd[k] * a[j - 1];
    Coefs c;
    c.b0 = (float)b[0]; c.b1 = (float)b[1]; c.b2 = (float)b[2];
    c.b3 = (float)b[3]; c.b4 = (float)b[4];
    c.a1 = (float)a[1].real(); c.a2 = (float)a[2].real();
    c.a3 = (float)a[3].real(); c.a4 = (float)a[4].real();
    return c;
}

} // namespace

extern "C" void kernel_launch(void* const* d_in, const int* in_sizes, int n_in,
                              void* d_out, int out_size, void* d_ws, size_t ws_size,
                              hipStream_t stream) {
    (void)in_sizes; (void)n_in; (void)d_ws; (void)ws_size;
    const float* x = (const float*)d_in[0];
    float* y = (float*)d_out;
    Coefs c = make_coefs();
    const int nblocks = out_size / REGION;   // 256*65536/8192 = 2048
    butter_kernel<<<nblocks, NT, 0, stream>>>(x, y, c);
}